// Round 9
// baseline (1079.292 us; speedup 1.0000x reference)
//
#include <hip/hip_runtime.h>

// EUNN: 256 layers; each layer = rotation on even pairs (2i,2i+1), then
// rotation on odd pairs (2i+1,2i+2 mod H).
// Pair math: y0 = e^{i*phi} (ct*u - st*v); y1 = st*u + ct*v.
//
// Journal: R1 423us (RPW=4, grid 256, 1 wave/SIMD). R2/R6: register coef
// double-buffer => allocator collapse (~60 VGPR) => 546-1080us. R3: (256,4)
// VGPR squeeze => 526us. R4: RPW=2, grid 512, (256,2), straight-line => 370us,
// VALUBusy 64%, VGPR 76 (best structure). R5: LDS staging + per-layer barrier
// => 431us. R7: scalar float2 hoping for SLP => no change (373us). R8: inline
// asm v_pk_* => allocator collapse again (536us, VGPR 60).
// RULE: only straight-line code over plain locals with constant indices.
// R9 (this): native <2 x float> arithmetic, two batch rows packed into the
// v2f lanes (SoA) so every rot op is uniform => backend ISel emits
// v_pk_mul_f32/v_pk_fma_f32 (packed fp32) without asm: 6 VALU/pair/row.

#define H_DIM 1024
#define C2 256
// 2 batch rows per wave, packed into v2f lanes.

typedef float v2f __attribute__((ext_vector_type(2)));
typedef float v4f __attribute__((ext_vector_type(4)));

// coef layout: [c][j][lane] as float4 (ct, st, cp, sp); j in [0,16):
//   j=0..7  : phase A pair (local 2j, 2j+1) of lane
//   j=8..14 : phase B internal pair (local 2j-15, 2j-14)
//   j=15    : phase B boundary pair (lane elem15, next lane's elem0)
// flat float4 index: (c*16 + j)*64 + lane,  16 KB per layer, 4 MB total.

__global__ __launch_bounds__(256) void eunn_coef_kernel(
    const float* __restrict__ phi0, const float* __restrict__ theta0,
    const float* __restrict__ phi1, const float* __restrict__ theta1,
    float4* __restrict__ coef) {
    int t = blockIdx.x * 256 + threadIdx.x;   // [0, 262144)
    int c = t & 255;                          // layer in low bits -> coalesced reads
    int ip = t >> 8;                          // [0,1024)
    int i = ip >> 1;                          // pair index [0,512)
    int p = ip & 1;                           // phase
    const float* phi   = p ? phi1   : phi0;
    const float* theta = p ? theta1 : theta0;
    float ph = phi[i * C2 + c];
    float th = theta[i * C2 + c];
    float sp, cp, st, ct;
    __sincosf(ph, &sp, &cp);
    __sincosf(th, &st, &ct);
    int j = (i & 7) + 8 * p;                  // j slot: A pairs 0..7, B pairs 8..15
    int l = i >> 3;
    coef[((c * 16) + j) * 64 + l] = make_float4(ct, st, cp, sp);
}

// Rotation on one pair for BOTH packed rows. All ops are <2 x float>;
// scalar coef components splat. 12 v2f instructions = 6 per pair per row.
__device__ __forceinline__ void rot_pair_v2(const v4f q,
                                            v2f& ur, v2f& ui,
                                            v2f& wr, v2f& wi) {
    // q = (ct, st, cp, sp)
    v2f ar = q.x * ur - q.y * wr;   // a = ct*u - st*w
    v2f ai = q.x * ui - q.y * wi;
    v2f br = q.y * ur + q.x * wr;   // b = st*u + ct*w
    v2f bi = q.y * ui + q.x * wi;
    ur = q.z * ar - q.w * ai;       // u' = e^{i phi} * a
    ui = q.w * ar + q.z * ai;
    wr = br;
    wi = bi;
}

// NOTE (R3): keep min-waves at 2. NOTE (R2/R6/R8): no coef double-buffer,
// no lambdas/macros/inline-asm — straight-line only.
__global__ __launch_bounds__(256, 2) void eunn_main_kernel(
    const float* __restrict__ x,
    const v4f* __restrict__ coef,
    float* __restrict__ out) {
    const int lane = threadIdx.x & 63;
    const int wave = threadIdx.x >> 6;
    const int row0 = (blockIdx.x * 4 + wave) * 2;

    // lane owns complex elements [16*lane, 16*lane+16) of rows row0, row0+1;
    // v2f lanes hold (row0, row1).
    v2f vre[16], vim[16];

    {
        const v4f* s0 = (const v4f*)(x + (size_t)(row0 + 0) * (H_DIM * 2)) + lane * 8;
        const v4f* s1 = (const v4f*)(x + (size_t)(row0 + 1) * (H_DIM * 2)) + lane * 8;
#pragma unroll
        for (int m = 0; m < 8; ++m) {
            v4f f0 = s0[m];
            v4f f1 = s1[m];
            vre[2 * m]     = (v2f){f0.x, f1.x};
            vim[2 * m]     = (v2f){f0.y, f1.y};
            vre[2 * m + 1] = (v2f){f0.z, f1.z};
            vim[2 * m + 1] = (v2f){f0.w, f1.w};
        }
    }

    const v4f* cl = coef + lane;   // lane-offset base, strength-reduced in loop

#pragma unroll 1
    for (int c = 0; c < C2; ++c) {
        const v4f* ca = cl + (size_t)c * 1024;

        // boundary coef for phase B, loaded up front; prev-lane copy via shuffle
        v4f qq = ca[15 * 64];
        float qpx = __shfl(qq.x, (lane + 63) & 63);   // prev lane's ct'
        float qpy = __shfl(qq.y, (lane + 63) & 63);   // prev lane's st'

        // --- phase A, boundary-adjacent pairs first (j=0 and j=7) so the
        // cross-lane shuffles can issue early and hide under the FMA work.
        {
            v4f q0 = ca[0 * 64];
            v4f q7 = ca[7 * 64];
            rot_pair_v2(q0, vre[0],  vim[0],  vre[1],  vim[1]);
            rot_pair_v2(q7, vre[14], vim[14], vre[15], vim[15]);
        }
        // post-phase-A elem0 / elem15 feed the phase-B boundary pair
        v2f nbr, nbi, pbr, pbi;
        nbr.x = __shfl(vre[0].x,  (lane + 1)  & 63);   // next lane's elem0 (row0)
        nbr.y = __shfl(vre[0].y,  (lane + 1)  & 63);   // (row1)
        nbi.x = __shfl(vim[0].x,  (lane + 1)  & 63);
        nbi.y = __shfl(vim[0].y,  (lane + 1)  & 63);
        pbr.x = __shfl(vre[15].x, (lane + 63) & 63);   // prev lane's elem15
        pbr.y = __shfl(vre[15].y, (lane + 63) & 63);
        pbi.x = __shfl(vim[15].x, (lane + 63) & 63);
        pbi.y = __shfl(vim[15].y, (lane + 63) & 63);

        // --- phase A remaining pairs j=1..6
#pragma unroll
        for (int j = 1; j < 7; ++j) {
            v4f q = ca[j * 64];
            rot_pair_v2(q, vre[2 * j], vim[2 * j], vre[2 * j + 1], vim[2 * j + 1]);
        }

        // --- phase B internal pairs (local 2j+1, 2j+2), j=0..6
#pragma unroll
        for (int j = 0; j < 7; ++j) {
            v4f q = ca[(8 + j) * 64];
            rot_pair_v2(q, vre[2 * j + 1], vim[2 * j + 1], vre[2 * j + 2], vim[2 * j + 2]);
        }

        // --- phase B boundary pair (my elem15, next lane's elem0): both
        // sides computed locally from the pre-issued shuffles.
        {
            v2f ar = qq.x * vre[15] - qq.y * nbr;   // ct*e15 - st*next_e0
            v2f ai = qq.x * vim[15] - qq.y * nbi;
            vre[15] = qq.z * ar - qq.w * ai;        // * e^{i phi}
            vim[15] = qq.w * ar + qq.z * ai;
            vre[0] = qpx * vre[0] + qpy * pbr;      // st'*prev_e15 + ct'*e0
            vim[0] = qpx * vim[0] + qpy * pbi;
        }
    }

    {
        v4f* d0 = (v4f*)(out + (size_t)(row0 + 0) * (H_DIM * 2)) + lane * 8;
        v4f* d1 = (v4f*)(out + (size_t)(row0 + 1) * (H_DIM * 2)) + lane * 8;
#pragma unroll
        for (int m = 0; m < 8; ++m) {
            d0[m] = (v4f){vre[2 * m].x, vim[2 * m].x, vre[2 * m + 1].x, vim[2 * m + 1].x};
            d1[m] = (v4f){vre[2 * m].y, vim[2 * m].y, vre[2 * m + 1].y, vim[2 * m + 1].y};
        }
    }
}

extern "C" void kernel_launch(void* const* d_in, const int* in_sizes, int n_in,
                              void* d_out, int out_size, void* d_ws, size_t ws_size,
                              hipStream_t stream) {
    const float* x      = (const float*)d_in[0];
    const float* phi0   = (const float*)d_in[1];
    const float* theta0 = (const float*)d_in[2];
    const float* phi1   = (const float*)d_in[3];
    const float* theta1 = (const float*)d_in[4];
    float* out = (float*)d_out;
    float4* coef = (float4*)d_ws;   // 256 layers * 16 * 64 float4 = 4 MB

    // coefficients: 256 layers * 2 phases * 512 pairs = 262144 threads
    hipLaunchKernelGGL(eunn_coef_kernel, dim3(1024), dim3(256), 0, stream,
                       phi0, theta0, phi1, theta1, coef);

    // main: 4096 rows / (4 waves/block * 2 rows/wave) = 512 blocks
    hipLaunchKernelGGL(eunn_main_kernel, dim3(512), dim3(256), 0, stream,
                       x, (const v4f*)coef, out);
}